// Round 12
// baseline (4645.394 us; speedup 1.0000x reference)
//
#include <hip/hip_runtime.h>

typedef _Float16 h2_t __attribute__((ext_vector_type(2)));

#define HID  100
#define TENC 4096
#define TDEC 4096
#define NCLS 6
#define NSTEP (TENC + TDEC - 1)   // 8191 recurrence steps
#define NTHR 320                  // 4 compute waves + 1 DMA wave

__device__ __forceinline__ float sigm(float v)  { return __builtin_amdgcn_rcpf(1.0f + __expf(-v)); }
__device__ __forceinline__ float tanh_(float v) { return 1.0f - 2.0f * __builtin_amdgcn_rcpf(1.0f + __expf(2.0f * v)); }

// lgkm-only barrier for compute waves: does NOT drain vmcnt -> hsto stores stay in flight.
#define SYNC_LDS() asm volatile("s_waitcnt lgkmcnt(0)\n\ts_barrier" ::: "memory")

typedef __attribute__((address_space(1))) const void gbl_v;
typedef __attribute__((address_space(3))) void       lds_v;

__device__ __forceinline__ float packh2(float a, float b) {
    h2_t p; p[0] = (_Float16)a; p[1] = (_Float16)b;
    return __builtin_bit_cast(float, p);
}

// Precompute gate-input streams: gxs[st][cell] = (i,f,g,o) of
// Wih @ input_st + bih + bhh, packed 4 x f16 = uint2 (8 B).
__global__ __launch_bounds__(256)
void gx_k(const float* __restrict__ x, const int* __restrict__ y,
          const float* __restrict__ eWih, const float* __restrict__ ebih,
          const float* __restrict__ ebhh, const float* __restrict__ dWih,
          const float* __restrict__ dbih, const float* __restrict__ dbhh,
          uint2* __restrict__ gxs)
{
    const int idx = blockIdx.x * 256 + threadIdx.x;
    if (idx >= NSTEP * HID) return;
    const int st   = idx / HID;
    const int cell = idx - st * HID;
    float g[4];
    if (st < TENC) {
        const float x0 = x[3*st], x1 = x[3*st+1], x2 = x[3*st+2];
        #pragma unroll
        for (int r = 0; r < 4; ++r) {
            const int row = cell + r * HID;
            g[r] = eWih[row*3]*x0 + eWih[row*3+1]*x1 + eWih[row*3+2]*x2
                 + ebih[row] + ebhh[row];
        }
    } else {
        const float yf = (float)y[st - TENC];
        #pragma unroll
        for (int r = 0; r < 4; ++r) {
            const int row = cell + r * HID;
            g[r] = dWih[row]*yf + dbih[row] + dbhh[row];
        }
    }
    uint2 u;
    u.x = __builtin_bit_cast(unsigned, packh2(g[0], g[1]));
    u.y = __builtin_bit_cast(unsigned, packh2(g[2], g[3]));
    gxs[idx] = u;
}

// v9 = R11 skeleton (validated: DMA-wave gx via global_load_lds, lgkm-only
// barrier, single body, no compute-wave VMEM loads) + v_pk_fma_f16 dot
// kernel. R11 falsified the VGPR-residency theory (VGPR 72 == R7's 116
// perf: AGPR shuttle rides the MFMA pipe, m114). Remaining VALU ~640
// cyc/step implies v_dot2_f32_f16 ~4-cyc issue; v_pk_fma_f16 (VOP3P packed
// math) does the same 2 MACs/inst at full rate. Each gate accumulates in
// TWO f16 sub-accs (13/12 pairs) -> pk_add -> f32 finish + gx seed.
// float4 h-loads consumed directly (no staging array).
__global__ __launch_bounds__(NTHR, 1)
void lstm_rec(const float* __restrict__ eWhh,   // [400*HID]
              const float* __restrict__ dWhh,   // [400*HID]
              const uint2* __restrict__ gxs,    // [NSTEP+8][HID]
              float* __restrict__ hsto)         // [(TDEC-1)*HID]
{
    __shared__ __align__(16) _Float16 hbuf[2][2][64];   // [parity][k-half][50 used]
    __shared__ __align__(16) uint2    gxring[8][HID];   // 8 x 800 B gx ring

    const int  t    = threadIdx.x;
    const int  w    = t >> 6;
    const int  l    = t & 63;
    const int  ci   = l & 31;
    const int  half = l >> 5;
    const int  cell = w * 32 + ci;                 // w==4 -> live=false
    const bool live = (cell < HID);
    const bool gldr = live && (half == 1);         // gx consumer / hsto writer
    const int  k0   = half * 50;

    float wf[4][25];
    float c = 0.0f;

    if (t < 256) ((_Float16*)hbuf)[t] = (_Float16)0.0f;

    #pragma unroll
    for (int r = 0; r < 4; ++r)
        #pragma unroll
        for (int j = 0; j < 25; ++j) wf[r][j] = 0.0f;
    if (live) {
        #pragma unroll
        for (int r = 0; r < 4; ++r) {
            const int row = cell + r * HID;
            #pragma unroll
            for (int j = 0; j < 25; ++j)
                wf[r][j] = packh2(eWhh[row*HID + k0 + 2*j], eWhh[row*HID + k0 + 2*j + 1]);
        }
    }

    // ---- DMA prelude: fill ring slots 0..3 (drained by __syncthreads) ----
    if (w == 4) {
        #pragma unroll
        for (int st = 0; st < 4; ++st)
            if (l < 50)
                __builtin_amdgcn_global_load_lds((gbl_v*)&gxs[st * HID + 2 * l],
                                                 (lds_v*)&gxring[st][0], 16, 0, 0);
    }
    __syncthreads();

    // ================ DMA wave: 8191 paired barriers ================
    if (w == 4) {
        for (int s = 0; s < NSTEP; ++s) {
            if (l < 50)
                __builtin_amdgcn_global_load_lds((gbl_v*)&gxs[(s + 4) * HID + 2 * l],
                                                 (lds_v*)&gxring[(s + 4) & 7][0], 16, 0, 0);
            asm volatile("s_waitcnt vmcnt(3)\n\ts_barrier" ::: "memory");
        }
        return;
    }

    int p = 0;

    // one step body: pk_fma dual-sub-accumulator dot + activation + publish
    #define DOT_AND_UPDATE(GX_SLOT, DO_HSTO, HSTO_IDX)                                  \
    {                                                                                   \
        const float4* h4 = (const float4*)&hbuf[p][half][0];                            \
        const float4 hv0 = h4[0], hv1 = h4[1], hv2 = h4[2];                             \
        const float4 hv3 = h4[3], hv4 = h4[4], hv5 = h4[5];                             \
        const float  h24 = ((const float*)h4)[24];                                      \
        float s0 = 0.f, s1 = 0.f, s2 = 0.f, s3 = 0.f;                                   \
        if (half == 1) {                                                                \
            const uint2 gxv = *(const uint2*)&gxring[(GX_SLOT)][cell];                  \
            const h2_t g01 = __builtin_bit_cast(h2_t, gxv.x);                           \
            const h2_t g23 = __builtin_bit_cast(h2_t, gxv.y);                           \
            s0 = (float)g01[0]; s1 = (float)g01[1];                                     \
            s2 = (float)g23[0]; s3 = (float)g23[1];                                     \
        }                                                                               \
        h2_t A0[4], A1[4];                                                              \
        _Pragma("unroll")                                                               \
        for (int r = 0; r < 4; ++r) { A0[r] = (h2_t)(_Float16)0.0f; A1[r] = (h2_t)(_Float16)0.0f; } \
        const float hw[25] = { hv0.x, hv0.y, hv0.z, hv0.w, hv1.x, hv1.y, hv1.z, hv1.w,  \
                               hv2.x, hv2.y, hv2.z, hv2.w, hv3.x, hv3.y, hv3.z, hv3.w,  \
                               hv4.x, hv4.y, hv4.z, hv4.w, hv5.x, hv5.y, hv5.z, hv5.w, h24 }; \
        _Pragma("unroll")                                                               \
        for (int j = 0; j < 12; ++j) {                                                  \
            const h2_t hh = __builtin_bit_cast(h2_t, hw[j]);                            \
            _Pragma("unroll")                                                           \
            for (int r = 0; r < 4; ++r)                                                 \
                A0[r] = __builtin_bit_cast(h2_t, wf[r][j]) * hh + A0[r];                \
        }                                                                               \
        _Pragma("unroll")                                                               \
        for (int j = 12; j < 24; ++j) {                                                 \
            const h2_t hh = __builtin_bit_cast(h2_t, hw[j]);                            \
            _Pragma("unroll")                                                           \
            for (int r = 0; r < 4; ++r)                                                 \
                A1[r] = __builtin_bit_cast(h2_t, wf[r][j]) * hh + A1[r];                \
        }                                                                               \
        { const h2_t hh = __builtin_bit_cast(h2_t, hw[24]);                             \
          _Pragma("unroll")                                                             \
          for (int r = 0; r < 4; ++r)                                                   \
              A0[r] = __builtin_bit_cast(h2_t, wf[r][24]) * hh + A0[r]; }               \
        float a0, a1, a2, a3;                                                           \
        { const h2_t z0 = A0[0] + A1[0]; a0 = s0 + (float)z0[0] + (float)z0[1]; }       \
        { const h2_t z1 = A0[1] + A1[1]; a1 = s1 + (float)z1[0] + (float)z1[1]; }       \
        { const h2_t z2 = A0[2] + A1[2]; a2 = s2 + (float)z2[0] + (float)z2[1]; }       \
        { const h2_t z3 = A0[3] + A1[3]; a3 = s3 + (float)z3[0] + (float)z3[1]; }       \
        a0 += __shfl_xor(a0, 32);                                                       \
        a1 += __shfl_xor(a1, 32);                                                       \
        a2 += __shfl_xor(a2, 32);                                                       \
        a3 += __shfl_xor(a3, 32);                                                       \
        const float fi = sigm(a0), ff = sigm(a1), fg = tanh_(a2), fo = sigm(a3);        \
        c = ff * c + fi * fg;                                                           \
        const float hn = fo * tanh_(c);                                                 \
        if (live) {                                                                     \
            if (half == 0) {                                                            \
                const int hh2 = (cell < 50) ? 0 : 1;                                    \
                hbuf[p ^ 1][hh2][cell - 50*hh2] = (_Float16)hn;                         \
            } else if (DO_HSTO) {                                                       \
                hsto[(HSTO_IDX) * HID + cell] = hn;                                     \
            }                                                                           \
        }                                                                               \
        SYNC_LDS();                                                                     \
        p ^= 1;                                                                         \
    }

    // ================ encoder: 4096 steps ================
    for (int s = 0; s < TENC; ++s)
        DOT_AND_UPDATE(s & 7, false, 0)

    // ================ swap to decoder weights (no barrier; DMA waits at its own) ================
    if (live) {
        #pragma unroll
        for (int r = 0; r < 4; ++r) {
            const int row = cell + r * HID;
            #pragma unroll
            for (int j = 0; j < 25; ++j)
                wf[r][j] = packh2(dWhh[row*HID + k0 + 2*j], dWhh[row*HID + k0 + 2*j + 1]);
        }
    }

    // ================ decoder: 4095 steps (ratio==1 -> teacher-forced) ================
    for (int s = 0; s < TDEC - 1; ++s)
        DOT_AND_UPDATE(s & 7, true, s)     // global step TENC+s; TENC%8==0 -> slot s&7

    #undef DOT_AND_UPDATE
}

// Parallel logits: out[t][r] = linW[r] . h_t + linb[r], last row zeroed.
__global__ __launch_bounds__(256)
void logits_k(const float* __restrict__ hsto, const float* __restrict__ linW,
              const float* __restrict__ linb, float* __restrict__ out)
{
    const int idx = blockIdx.x * 256 + threadIdx.x;
    if (idx >= TDEC * NCLS) return;
    const int tt = idx / NCLS;
    const int r  = idx % NCLS;
    if (tt >= TDEC - 1) { out[idx] = 0.0f; return; }
    const float* h  = hsto + tt * HID;
    const float* wr = linW + r * HID;
    float a = linb[r];
    #pragma unroll 4
    for (int k = 0; k < HID; ++k) a += wr[k] * h[k];
    out[idx] = a;
}

extern "C" void kernel_launch(void* const* d_in, const int* in_sizes, int n_in,
                              void* d_out, int out_size, void* d_ws, size_t ws_size,
                              hipStream_t stream)
{
    const float* x    = (const float*)d_in[0];
    const int*   y    = (const int*)  d_in[1];
    const float* eWih = (const float*)d_in[2];
    const float* eWhh = (const float*)d_in[3];
    const float* ebih = (const float*)d_in[4];
    const float* ebhh = (const float*)d_in[5];
    const float* dWih = (const float*)d_in[6];
    const float* dWhh = (const float*)d_in[7];
    const float* dbih = (const float*)d_in[8];
    const float* dbhh = (const float*)d_in[9];
    const float* linW = (const float*)d_in[10];
    const float* linb = (const float*)d_in[11];
    float* out  = (float*)d_out;

    float* hsto = (float*)d_ws;                                   // 1.64 MB
    uint2* gxs  = (uint2*)((char*)d_ws + (2u << 20));             // (NSTEP+8)*HID*8 = 6.56 MB

    const int ngx = NSTEP * HID;
    gx_k<<<dim3((ngx + 255) / 256), dim3(256), 0, stream>>>(
        x, y, eWih, ebih, ebhh, dWih, dbih, dbhh, gxs);

    lstm_rec<<<dim3(1), dim3(NTHR), 0, stream>>>(eWhh, dWhh, gxs, hsto);

    const int nout = TDEC * NCLS;
    logits_k<<<dim3((nout + 255) / 256), dim3(256), 0, stream>>>(hsto, linW, linb, out);
}